// Round 2
// baseline (1835.965 us; speedup 1.0000x reference)
//
#include <hip/hip_runtime.h>
#include <math.h>

// Problem constants
#define BB    256
#define NMAX  512
#define HH    256   // H
#define CC    64    // C
#define HID   512
#define NEGV  -1000000000.0f
#define MT    64    // d-rows per mlp block
#define NW    8     // waves per block (512 threads)
#define SA_LD 264   // A-tile leading dim: 256 + 8 pad (bf16 elems)
#define TILE  512   // ushorts per swizzled (16n x 32k) weight tile = 1KB
#define KSTR  (32 * TILE)  // ushorts per kb slab (32 n-tiles)

// LDS union layout (ushort units):
//   [0, 16896)           A-tile 64 x SA_LD bf16 (33,792 B); later reused as s_red
//   [16896, 20992)       chunk buf 0: 4096 ushorts (8 KB)
//   [20992, 25088)       chunk buf 1: 4096 ushorts (8 KB)
#define CHUNK_OFF 16896
#define CHUNK_SZ  4096
#define SU_USHORT (CHUNK_OFF + 2 * CHUNK_SZ)   // 25088 ushorts = 50,176 B

typedef __attribute__((ext_vector_type(8))) short short8;   // 8 bf16 = 4 VGPRs
typedef __attribute__((ext_vector_type(4))) float floatx4;  // MFMA C/D

__device__ inline ushort f2bf(float x) {
    unsigned u = __float_as_uint(x);
    u = (u + 0x7FFFu + ((u >> 16) & 1u)) >> 16;   // RNE
    return (ushort)u;
}

// ---------------------------------------------------------------------------
// Fused prep kernel, grid = 512 blocks x 256 threads (unchanged this round):
//   blocks [0,128):   convert W1 k-rows [0,512) -> swizzled lane-order bf16
//   blocks [128,256): convert W2 -> swizzled lane-order bf16
//   blocks [256,512): per-batch base vector v_b (fp32 exact)
// ---------------------------------------------------------------------------
__global__ __launch_bounds__(256) void prep_kernel(
    const float* __restrict__ W1, const float* __restrict__ W2,
    ushort* __restrict__ Wt1s, ushort* __restrict__ Wt2s,
    const float* __restrict__ nodes_hv, const float* __restrict__ class_cond,
    const float* __restrict__ b1,
    const int* __restrict__ dirns, const int* __restrict__ node_counts,
    float* __restrict__ v_ws)
{
    const int blk = blockIdx.x;
    const int t = threadIdx.x;

    __shared__ float s_conv[32][68];
    __shared__ float s_src[HH];
    __shared__ float s_cc[CC];

    if (blk < 256) {
        const float* W = (blk < 128) ? W1 : W2;
        ushort* out    = (blk < 128) ? Wt1s : Wt2s;
        const int bb  = blk & 127;
        const int kb  = bb >> 3, ntg = bb & 7;

        {
            const int kl = t >> 3, nn = (t & 7) * 8;
            const float* src = W + (size_t)(kb * 32 + kl) * HID + ntg * 64 + nn;
            *(float4*)&s_conv[kl][nn]     = *(const float4*)src;
            *(float4*)&s_conv[kl][nn + 4] = *(const float4*)(src + 4);
        }
        __syncthreads();

        const int ntl = t >> 6, ls = t & 63;
        const int qs = ls >> 4, l15s = ls & 15;
        short8 o;
        #pragma unroll
        for (int j = 0; j < 8; ++j)
            o[j] = (short)f2bf(s_conv[qs * 8 + j][ntl * 16 + l15s]);
        const int nt = ntg * 4 + ntl;
        *(short8*)(out + ((size_t)(kb * 32 + nt)) * TILE + ls * 8) = o;
    } else {
        const int b = blk - 256;
        const int nc   = node_counts[b];
        const int dirn = dirns[b];
        const int src_idx = nc - 1;

        s_src[t] = nodes_hv[((size_t)b * NMAX + src_idx) * HH + t];
        if (t < CC) s_cc[t] = class_cond[b * CC + t];
        __syncthreads();

        const int srcoff = (dirn == 1) ? HH : 0;

        const int j = 2 * t;
        float acc0 = b1[j];
        float acc1 = b1[j + 1];

        #pragma unroll 4
        for (int r = 0; r < HH; ++r) {
            const float s = s_src[r];
            const float* wp = W1 + (size_t)(srcoff + r) * HID + j;
            acc0 += s * wp[0];
            acc1 += s * wp[1];
        }
        #pragma unroll 4
        for (int c = 0; c < CC; ++c) {
            const float s = s_cc[c];
            const float* wp = W1 + (size_t)(2 * HH + c) * HID + j;
            acc0 += s * wp[0];
            acc1 += s * wp[1];
        }
        v_ws[b * HID + j]     = acc0;
        v_ws[b * HID + j + 1] = acc1;
    }
}

// ---------------------------------------------------------------------------
// h1 chunk writer: wave wv's layer-1 acc (n-chunk [wv*64,+64)) -> fragment-tiled
// chunk buffer. Layout: off(mb,ksl,L,j) = ((mb*2+ksl)*64 + L)*8 + j holds
// h1[row = mb*16 + (L&15)][k_local = ksl*32 + (L>>4)*8 + j], so layer-2's
// ds_read_b128 at ((mb*2+ksl)*64 + lane)*8 is the exact A-fragment.
// All indices compile-time (full unroll) -> stays in registers.
// ---------------------------------------------------------------------------
__device__ inline void write_chunk(ushort* __restrict__ dst,
                                   const floatx4 (&acc1)[4][4],
                                   const float (&vws)[4],
                                   int l15, int q)
{
    #pragma unroll
    for (int tn = 0; tn < 4; ++tn) {
        const float v = vws[tn];
        const int ksl = tn >> 1;
        const int qr  = ((tn & 1) << 1) + (l15 >> 3);
        const int jw  = l15 & 7;
        #pragma unroll
        for (int mb = 0; mb < 4; ++mb) {
            #pragma unroll
            for (int r = 0; r < 4; ++r) {
                float h = acc1[mb][tn][r] + v;          // C/D: row=q*4+r, col=l15
                h = h > 0.f ? h : 0.f;
                dst[((mb * 2 + ksl) * 64 + qr * 16 + q * 4 + r) * 8 + jw] = f2bf(h);
            }
        }
    }
}

// ---------------------------------------------------------------------------
// Kernel 2: MFMA MLP, M=64, 512 threads (8 waves). grid = (NMAX/MT, B).
// R8: chunk-streamed h1. Instead of materializing h1 (64x512 bf16 = 64 KB LDS,
// capping occupancy at 2 blocks/CU), stream it through two 8 KB chunk buffers:
// phase c consumes K-chunk [64c,+64) (produced by wave c) while wave c+1 writes
// chunk c+1 into the other buffer. LDS = 50 KB -> 3 blocks/CU (24 waves),
// giving cross-block phase diversity to hide L2 weight-load latency + barrier
// drains. Layer-2 weights are register-double-buffered across phases (global
// loads don't depend on the barrier). __launch_bounds__(512,6): 341-reg cap,
// ~230 needed (acc1+acc2 = 128, bfr dbuf 64).
// ---------------------------------------------------------------------------
__global__ __launch_bounds__(512, 6) void mlp2(
    const float* __restrict__ nodes_hv,
    const ushort* __restrict__ Wt1s, const ushort* __restrict__ Wt2s,
    const float* __restrict__ b2, const float* __restrict__ W3,
    const float* __restrict__ b3,
    const int* __restrict__ dirns, const int* __restrict__ node_counts,
    const float* __restrict__ v_ws, float* __restrict__ scores)
{
    const int b  = blockIdx.y;
    const int d0 = blockIdx.x * MT;
    const int t  = threadIdx.x;
    const int lane = t & 63, wv = t >> 6;     // wv in [0,8)
    const int l15 = lane & 15, q = lane >> 4;

    __shared__ ushort s_u[SU_USHORT];   // 50,176 B

    const int nc = node_counts[b];

    // Block-uniform early exit: whole tile masked off
    if (d0 >= nc - 1) {
        if (t < MT) scores[b * NMAX + d0 + t] = NEGV;
        return;
    }

    // dirn==1: cand occupies x[0:256) -> W1 k-rows [0:256) -> kb0=0; else kb0=8
    const int kb0 = (dirns[b] == 1) ? 0 : 8;

    // v_b values for this wave's n-chunk (needed at h1-write time) — load early
    float vws[4];
    #pragma unroll
    for (int tn = 0; tn < 4; ++tn)
        vws[tn] = v_ws[b * HID + wv * 64 + tn * 16 + l15];

    // ---- stage cand tile (MT x 256 fp32 -> bf16 LDS, leading dim SA_LD) ----
    {
        const float4* src4 = (const float4*)nodes_hv + ((size_t)b * NMAX + d0) * (HH / 4);
        #pragma unroll
        for (int i = 0; i < (MT * HH / 4) / 512; ++i) {   // 8 iters
            int idx = t + i * 512;
            int row = idx >> 6, c4 = idx & 63;
            float4 v = src4[idx];
            ushort4 p;
            p.x = f2bf(v.x); p.y = f2bf(v.y); p.z = f2bf(v.z); p.w = f2bf(v.w);
            *(ushort4*)&s_u[row * SA_LD + c4 * 4] = p;
        }
    }
    __syncthreads();

    floatx4 acc1[4][4];
    #pragma unroll
    for (int mb = 0; mb < 4; ++mb)
        #pragma unroll
        for (int tn = 0; tn < 4; ++tn)
            acc1[mb][tn] = (floatx4){0.f, 0.f, 0.f, 0.f};

    // ---- layer 1: K = 256 (8 K-steps of 32) ----
    {
        const ushort* wb1 = Wt1s + ((size_t)kb0 * 32 + wv * 4) * TILE + lane * 8;
        #pragma unroll
        for (int ks = 0; ks < 8; ++ks) {
            const ushort* wp = wb1 + (size_t)ks * KSTR;
            short8 bfr[4];
            #pragma unroll
            for (int tn = 0; tn < 4; ++tn)
                bfr[tn] = *(const short8*)(wp + tn * TILE);
            short8 a[4];
            #pragma unroll
            for (int mb = 0; mb < 4; ++mb)
                a[mb] = *(const short8*)&s_u[(mb * 16 + l15) * SA_LD + ks * 32 + q * 8];
            #pragma unroll
            for (int tn = 0; tn < 4; ++tn)
                #pragma unroll
                for (int mb = 0; mb < 4; ++mb)
                    acc1[mb][tn] = __builtin_amdgcn_mfma_f32_16x16x32_bf16(a[mb], bfr[tn], acc1[mb][tn], 0, 0, 0);
        }
    }
    // NOTE: no barrier here — chunk buffers are disjoint from the A-tile, so
    // wave 0 can publish chunk 0 while other waves finish layer 1.

    ushort* cb0 = s_u + CHUNK_OFF;
    ushort* cb1 = cb0 + CHUNK_SZ;

    floatx4 acc2[4][4];
    #pragma unroll
    for (int mb = 0; mb < 4; ++mb)
        #pragma unroll
        for (int tn = 0; tn < 4; ++tn)
            acc2[mb][tn] = (floatx4){0.f, 0.f, 0.f, 0.f};

    const ushort* wb2 = Wt2s + ((size_t)wv * 4) * TILE + lane * 8;

    // prefetch phase-0 weights (k rows [0,64)): i = ksl*4 + tn
    short8 bfA[8], bfB[8];
    #pragma unroll
    for (int i = 0; i < 8; ++i)
        bfA[i] = *(const short8*)(wb2 + (size_t)(i >> 2) * KSTR + (i & 3) * TILE);

    if (wv == 0) write_chunk(cb0, acc1, vws, l15, q);
    __syncthreads();   // chunk 0 visible; all waves done with layer 1 / A-tile

    // ---- layer 2: K = 512 as 8 phases of 64 (chunk c from wave c) ----
    #pragma unroll
    for (int c = 0; c < 8; ++c) {
        short8* cur = (c & 1) ? bfB : bfA;
        short8* nxt = (c & 1) ? bfA : bfB;
        if (c < 7) {
            // issue next phase's weight loads first (L2 latency hides under MFMAs)
            #pragma unroll
            for (int i = 0; i < 8; ++i)
                nxt[i] = *(const short8*)(wb2 + (size_t)((c + 1) * 2 + (i >> 2)) * KSTR + (i & 3) * TILE);
            // producer: wave c+1 publishes chunk c+1 into the other buffer
            if (wv == c + 1) write_chunk((c & 1) ? cb0 : cb1, acc1, vws, l15, q);
        }
        ushort* rb = (c & 1) ? cb1 : cb0;
        #pragma unroll
        for (int ksl = 0; ksl < 2; ++ksl) {
            short8 a[4];
            #pragma unroll
            for (int mb = 0; mb < 4; ++mb)
                a[mb] = *(const short8*)&rb[((mb * 2 + ksl) * 64 + lane) * 8];
            #pragma unroll
            for (int tn = 0; tn < 4; ++tn)
                #pragma unroll
                for (int mb = 0; mb < 4; ++mb)
                    acc2[mb][tn] = __builtin_amdgcn_mfma_f32_16x16x32_bf16(a[mb], cur[ksl * 4 + tn], acc2[mb][tn], 0, 0, 0);
        }
        __syncthreads();   // next chunk published + everyone done reading rb
    }

    // ---- epilogue 2: p = relu(acc2 + b2) . W3, reduce over n ----
    const int n0 = wv * 64;
    float p[4][4] = {{0,0,0,0},{0,0,0,0},{0,0,0,0},{0,0,0,0}};
    #pragma unroll
    for (int tn = 0; tn < 4; ++tn) {
        const int n  = n0 + tn * 16 + l15;
        const float bb = b2[n];
        const float w3 = W3[n];
        #pragma unroll
        for (int mb = 0; mb < 4; ++mb)
            #pragma unroll
            for (int r = 0; r < 4; ++r) {
                float h = acc2[mb][tn][r] + bb;
                h = h > 0.f ? h : 0.f;
                p[mb][r] += h * w3;
            }
    }
    // A-tile region long dead (last phase barrier passed) — reuse for s_red
    float* s_red = (float*)s_u;   // [8 waves][MT]
    #pragma unroll
    for (int mb = 0; mb < 4; ++mb)
        #pragma unroll
        for (int r = 0; r < 4; ++r) {
            float v = p[mb][r];
            v += __shfl_xor(v, 1, 64);
            v += __shfl_xor(v, 2, 64);
            v += __shfl_xor(v, 4, 64);
            v += __shfl_xor(v, 8, 64);
            if (l15 == 0) s_red[wv * MT + mb * 16 + q * 4 + r] = v;
        }
    __syncthreads();
    if (t < MT) {
        float s = b3[0];
        #pragma unroll
        for (int w = 0; w < NW; ++w) s += s_red[w * MT + t];
        const int d = d0 + t;
        scores[b * NMAX + d] = (d < nc - 1) ? s : NEGV;
    }
}

// ---------------------------------------------------------------------------
// Kernel 3: per-batch masked log-softmax NLL. grid = B, block = 256.
// ---------------------------------------------------------------------------
__global__ __launch_bounds__(256) void loss_kernel(
    const float* __restrict__ scores, const int* __restrict__ dests,
    float* __restrict__ out)
{
    const int b = blockIdx.x;
    const int t = threadIdx.x;
    __shared__ float red[4];

    const float s0 = scores[b * NMAX + t];
    const float s1 = scores[b * NMAX + t + 256];

    const int lane = t & 63, wv = t >> 6;

    float mx = fmaxf(s0, s1);
    #pragma unroll
    for (int off = 32; off > 0; off >>= 1) mx = fmaxf(mx, __shfl_down(mx, off, 64));
    if (lane == 0) red[wv] = mx;
    __syncthreads();
    mx = fmaxf(fmaxf(red[0], red[1]), fmaxf(red[2], red[3]));
    __syncthreads();

    float e = __expf(s0 - mx) + __expf(s1 - mx);
    #pragma unroll
    for (int off = 32; off > 0; off >>= 1) e += __shfl_down(e, off, 64);
    if (lane == 0) red[wv] = e;
    __syncthreads();

    if (t == 0) {
        const float sum = red[0] + red[1] + red[2] + red[3];
        const float sd = scores[b * NMAX + dests[b]];
        out[b] = -(sd - mx - logf(sum));
    }
}

// ---------------------------------------------------------------------------
extern "C" void kernel_launch(void* const* d_in, const int* in_sizes, int n_in,
                              void* d_out, int out_size, void* d_ws, size_t ws_size,
                              hipStream_t stream) {
    const float* nodes_hv    = (const float*)d_in[0];
    const float* class_cond  = (const float*)d_in[1];
    const float* W1          = (const float*)d_in[2];
    const float* b1          = (const float*)d_in[3];
    const float* W2          = (const float*)d_in[4];
    const float* b2          = (const float*)d_in[5];
    const float* W3          = (const float*)d_in[6];
    const float* b3          = (const float*)d_in[7];
    const int*   dirns       = (const int*)d_in[8];
    const int*   node_counts = (const int*)d_in[9];
    const int*   dests       = (const int*)d_in[10];
    float* out = (float*)d_out;

    // ws layout (16B-aligned):
    //   Wt1s: 512 KiB | Wt2s: 512 KiB | v_ws: 512 KiB | scores: 512 KiB
    ushort* Wt1s   = (ushort*)d_ws;
    ushort* Wt2s   = Wt1s + 16 * KSTR;
    float*  v_ws   = (float*)(Wt2s + 16 * KSTR);
    float*  scores = v_ws + BB * HID;

    prep_kernel<<<512, 256, 0, stream>>>(W1, W2, Wt1s, Wt2s,
                                         nodes_hv, class_cond, b1,
                                         dirns, node_counts, v_ws);
    mlp2<<<dim3(NMAX / MT, BB), 512, 0, stream>>>(
        nodes_hv, Wt1s, Wt2s, b2, W3, b3, dirns, node_counts, v_ws, scores);
    loss_kernel<<<BB, 256, 0, stream>>>(scores, dests, out);
}

// Round 4
// 305.014 us; speedup vs baseline: 6.0193x; 6.0193x over previous
//
#include <hip/hip_runtime.h>
#include <math.h>

// Problem constants
#define BB    256
#define NMAX  512
#define HH    256   // H
#define CC    64    // C
#define HID   512
#define NEGV  -1000000000.0f
#define MT    64    // d-rows per mlp block
#define NW    8     // waves per block (512 threads)
#define SA_LD 264   // A-tile leading dim: 256 + 8 pad (bf16 elems)
#define TILE  512   // ushorts per swizzled (16n x 32k) weight tile = 1KB
#define KSTR  (32 * TILE)  // ushorts per kb slab (32 n-tiles)

typedef __attribute__((ext_vector_type(8))) short short8;   // 8 bf16 = 4 VGPRs
typedef __attribute__((ext_vector_type(4))) float floatx4;  // MFMA C/D

__device__ inline ushort f2bf(float x) {
    unsigned u = __float_as_uint(x);
    u = (u + 0x7FFFu + ((u >> 16) & 1u)) >> 16;   // RNE
    return (ushort)u;
}

// ---------------------------------------------------------------------------
// Fused prep kernel, grid = 512 blocks x 256 threads (unchanged):
//   blocks [0,128):   convert W1 k-rows [0,512) -> swizzled lane-order bf16
//   blocks [128,256): convert W2 -> swizzled lane-order bf16
//   blocks [256,512): per-batch base vector v_b (fp32 exact)
// ---------------------------------------------------------------------------
__global__ __launch_bounds__(256) void prep_kernel(
    const float* __restrict__ W1, const float* __restrict__ W2,
    ushort* __restrict__ Wt1s, ushort* __restrict__ Wt2s,
    const float* __restrict__ nodes_hv, const float* __restrict__ class_cond,
    const float* __restrict__ b1,
    const int* __restrict__ dirns, const int* __restrict__ node_counts,
    float* __restrict__ v_ws)
{
    const int blk = blockIdx.x;
    const int t = threadIdx.x;

    __shared__ float s_conv[32][68];
    __shared__ float s_src[HH];
    __shared__ float s_cc[CC];

    if (blk < 256) {
        const float* W = (blk < 128) ? W1 : W2;
        ushort* out    = (blk < 128) ? Wt1s : Wt2s;
        const int bb  = blk & 127;
        const int kb  = bb >> 3, ntg = bb & 7;

        {
            const int kl = t >> 3, nn = (t & 7) * 8;
            const float* src = W + (size_t)(kb * 32 + kl) * HID + ntg * 64 + nn;
            *(float4*)&s_conv[kl][nn]     = *(const float4*)src;
            *(float4*)&s_conv[kl][nn + 4] = *(const float4*)(src + 4);
        }
        __syncthreads();

        const int ntl = t >> 6, ls = t & 63;
        const int qs = ls >> 4, l15s = ls & 15;
        short8 o;
        #pragma unroll
        for (int j = 0; j < 8; ++j)
            o[j] = (short)f2bf(s_conv[qs * 8 + j][ntl * 16 + l15s]);
        const int nt = ntg * 4 + ntl;
        *(short8*)(out + ((size_t)(kb * 32 + nt)) * TILE + ls * 8) = o;
    } else {
        const int b = blk - 256;
        const int nc   = node_counts[b];
        const int dirn = dirns[b];
        const int src_idx = nc - 1;

        s_src[t] = nodes_hv[((size_t)b * NMAX + src_idx) * HH + t];
        if (t < CC) s_cc[t] = class_cond[b * CC + t];
        __syncthreads();

        const int srcoff = (dirn == 1) ? HH : 0;

        const int j = 2 * t;
        float acc0 = b1[j];
        float acc1 = b1[j + 1];

        #pragma unroll 4
        for (int r = 0; r < HH; ++r) {
            const float s = s_src[r];
            const float* wp = W1 + (size_t)(srcoff + r) * HID + j;
            acc0 += s * wp[0];
            acc1 += s * wp[1];
        }
        #pragma unroll 4
        for (int c = 0; c < CC; ++c) {
            const float s = s_cc[c];
            const float* wp = W1 + (size_t)(2 * HH + c) * HID + j;
            acc0 += s * wp[0];
            acc1 += s * wp[1];
        }
        v_ws[b * HID + j]     = acc0;
        v_ws[b * HID + j + 1] = acc1;
    }
}

// ---------------------------------------------------------------------------
// Kernel 2: MFMA MLP, M=64, 512 threads (8 waves). grid = (NMAX/MT, B).
// Structure = the verified 313 µs version (full h1 in 64 KB LDS union,
// 2 blocks/CU) + R9 change: depth-1 register double-buffer of weight tiles
// in both layer loops, with mb-outer MFMA order so the A-fragment is loaded
// just-in-time. Live regs ~ acc(64 AGPR) + bcur(16) + bnxt(16) + a(8) + addr
// fits the (512,4) 128-reg budget without spill. R8 post-mortem: chunk-
// streaming h1 with launch_bounds(512,6) capped regs at ~85 -> total spill
// (VGPR_Count 40, 4.3 GB scratch traffic, 12x slower). Do not lower the
// reg cap below 128 while two 64-reg accumulator sets or prefetch regs live.
// ---------------------------------------------------------------------------
__global__ __launch_bounds__(512, 4) void mlp2(
    const float* __restrict__ nodes_hv,
    const ushort* __restrict__ Wt1s, const ushort* __restrict__ Wt2s,
    const float* __restrict__ b2, const float* __restrict__ W3,
    const float* __restrict__ b3,
    const int* __restrict__ dirns, const int* __restrict__ node_counts,
    const float* __restrict__ v_ws, float* __restrict__ scores)
{
    const int b  = blockIdx.y;
    const int d0 = blockIdx.x * MT;
    const int t  = threadIdx.x;
    const int lane = t & 63, wv = t >> 6;     // wv in [0,8)
    const int l15 = lane & 15, q = lane >> 4;

    __shared__ ushort s_u[32768];   // 64 KB union

    const int nc = node_counts[b];

    // Block-uniform early exit: whole tile masked off
    if (d0 >= nc - 1) {
        if (t < MT) scores[b * NMAX + d0 + t] = NEGV;
        return;
    }

    // dirn==1: cand occupies x[0:256) -> W1 k-rows [0:256) -> kb0=0; else kb0=8
    const int kb0 = (dirns[b] == 1) ? 0 : 8;

    // ---- stage cand tile (MT x 256 fp32 -> bf16 LDS, leading dim SA_LD) ----
    {
        const float4* src4 = (const float4*)nodes_hv + ((size_t)b * NMAX + d0) * (HH / 4);
        #pragma unroll
        for (int i = 0; i < (MT * HH / 4) / 512; ++i) {   // 8 iters
            int idx = t + i * 512;
            int row = idx >> 6, c4 = idx & 63;
            float4 v = src4[idx];
            ushort4 p;
            p.x = f2bf(v.x); p.y = f2bf(v.y); p.z = f2bf(v.z); p.w = f2bf(v.w);
            *(ushort4*)&s_u[row * SA_LD + c4 * 4] = p;
        }
    }
    __syncthreads();

    floatx4 acc[4][4];
    #pragma unroll
    for (int mb = 0; mb < 4; ++mb)
        #pragma unroll
        for (int tn = 0; tn < 4; ++tn)
            acc[mb][tn] = (floatx4){0.f, 0.f, 0.f, 0.f};

    // ---- layer 1: K = 256 (8 K-steps of 32), depth-1 weight prefetch ----
    {
        const ushort* wb1 = Wt1s + ((size_t)kb0 * 32 + wv * 4) * TILE + lane * 8;
        short8 bcur[4], bnxt[4];
        #pragma unroll
        for (int tn = 0; tn < 4; ++tn)
            bcur[tn] = *(const short8*)(wb1 + tn * TILE);
        #pragma unroll
        for (int ks = 0; ks < 8; ++ks) {
            if (ks < 7) {
                const ushort* wp = wb1 + (size_t)(ks + 1) * KSTR;
                #pragma unroll
                for (int tn = 0; tn < 4; ++tn)
                    bnxt[tn] = *(const short8*)(wp + tn * TILE);
            }
            #pragma unroll
            for (int mb = 0; mb < 4; ++mb) {
                const short8 a = *(const short8*)&s_u[(mb * 16 + l15) * SA_LD + ks * 32 + q * 8];
                #pragma unroll
                for (int tn = 0; tn < 4; ++tn)
                    acc[mb][tn] = __builtin_amdgcn_mfma_f32_16x16x32_bf16(a, bcur[tn], acc[mb][tn], 0, 0, 0);
            }
            #pragma unroll
            for (int tn = 0; tn < 4; ++tn)
                bcur[tn] = bnxt[tn];
        }
    }
    __syncthreads();   // all waves done reading cand tile before h1 overwrites union

    const int n0 = wv * 64;

    // ---- epilogue 1: h1 = relu(acc + v_b) -> fragment-tiled LDS ----
    // n = n0 + tn*16 + l15 -> ks_w = wv*2 + (tn>>1); qr = ((tn&1)<<1)+(l15>>3); j_w = l15&7
    {
        const int j_w = l15 & 7;
        #pragma unroll
        for (int tn = 0; tn < 4; ++tn) {
            const int n = n0 + tn * 16 + l15;
            const float v = v_ws[b * HID + n];
            const int ks_w = wv * 2 + (tn >> 1);
            const int qr   = ((tn & 1) << 1) + (l15 >> 3);
            #pragma unroll
            for (int mb = 0; mb < 4; ++mb) {
                #pragma unroll
                for (int r = 0; r < 4; ++r) {
                    float h = acc[mb][tn][r] + v;          // C/D: row=q*4+r, col=l15
                    h = h > 0.f ? h : 0.f;
                    s_u[((mb * 16 + ks_w) * 64 + qr * 16 + q * 4 + r) * 8 + j_w] = f2bf(h);
                }
            }
        }
    }
    __syncthreads();

    // ---- layer 2: K = 512 (16 K-steps), depth-1 weight prefetch ----
    #pragma unroll
    for (int mb = 0; mb < 4; ++mb)
        #pragma unroll
        for (int tn = 0; tn < 4; ++tn)
            acc[mb][tn] = (floatx4){0.f, 0.f, 0.f, 0.f};
    {
        const ushort* wb2 = Wt2s + ((size_t)wv * 4) * TILE + lane * 8;
        short8 bcur[4], bnxt[4];
        #pragma unroll
        for (int tn = 0; tn < 4; ++tn)
            bcur[tn] = *(const short8*)(wb2 + tn * TILE);
        #pragma unroll
        for (int ks = 0; ks < 16; ++ks) {
            if (ks < 15) {
                const ushort* wp = wb2 + (size_t)(ks + 1) * KSTR;
                #pragma unroll
                for (int tn = 0; tn < 4; ++tn)
                    bnxt[tn] = *(const short8*)(wp + tn * TILE);
            }
            #pragma unroll
            for (int mb = 0; mb < 4; ++mb) {
                const short8 a = *(const short8*)&s_u[((mb * 16 + ks) * 64 + lane) * 8];
                #pragma unroll
                for (int tn = 0; tn < 4; ++tn)
                    acc[mb][tn] = __builtin_amdgcn_mfma_f32_16x16x32_bf16(a, bcur[tn], acc[mb][tn], 0, 0, 0);
            }
            #pragma unroll
            for (int tn = 0; tn < 4; ++tn)
                bcur[tn] = bnxt[tn];
        }
    }

    // ---- epilogue 2: p = relu(acc + b2) . W3, reduce over n ----
    float p[4][4] = {{0,0,0,0},{0,0,0,0},{0,0,0,0},{0,0,0,0}};
    #pragma unroll
    for (int tn = 0; tn < 4; ++tn) {
        const int n  = n0 + tn * 16 + l15;
        const float bb = b2[n];
        const float w3 = W3[n];
        #pragma unroll
        for (int mb = 0; mb < 4; ++mb)
            #pragma unroll
            for (int r = 0; r < 4; ++r) {
                float h = acc[mb][tn][r] + bb;
                h = h > 0.f ? h : 0.f;
                p[mb][r] += h * w3;
            }
    }
    __syncthreads();   // h1 region dead; safe to reuse union for s_red
    float* s_red = (float*)s_u;   // [8 waves][MT]
    #pragma unroll
    for (int mb = 0; mb < 4; ++mb)
        #pragma unroll
        for (int r = 0; r < 4; ++r) {
            float v = p[mb][r];
            v += __shfl_xor(v, 1, 64);
            v += __shfl_xor(v, 2, 64);
            v += __shfl_xor(v, 4, 64);
            v += __shfl_xor(v, 8, 64);
            if (l15 == 0) s_red[wv * MT + mb * 16 + q * 4 + r] = v;
        }
    __syncthreads();
    if (t < MT) {
        float s = b3[0];
        #pragma unroll
        for (int w = 0; w < NW; ++w) s += s_red[w * MT + t];
        const int d = d0 + t;
        scores[b * NMAX + d] = (d < nc - 1) ? s : NEGV;
    }
}

// ---------------------------------------------------------------------------
// Kernel 3: per-batch masked log-softmax NLL. grid = B, block = 256.
// ---------------------------------------------------------------------------
__global__ __launch_bounds__(256) void loss_kernel(
    const float* __restrict__ scores, const int* __restrict__ dests,
    float* __restrict__ out)
{
    const int b = blockIdx.x;
    const int t = threadIdx.x;
    __shared__ float red[4];

    const float s0 = scores[b * NMAX + t];
    const float s1 = scores[b * NMAX + t + 256];

    const int lane = t & 63, wv = t >> 6;

    float mx = fmaxf(s0, s1);
    #pragma unroll
    for (int off = 32; off > 0; off >>= 1) mx = fmaxf(mx, __shfl_down(mx, off, 64));
    if (lane == 0) red[wv] = mx;
    __syncthreads();
    mx = fmaxf(fmaxf(red[0], red[1]), fmaxf(red[2], red[3]));
    __syncthreads();

    float e = __expf(s0 - mx) + __expf(s1 - mx);
    #pragma unroll
    for (int off = 32; off > 0; off >>= 1) e += __shfl_down(e, off, 64);
    if (lane == 0) red[wv] = e;
    __syncthreads();

    if (t == 0) {
        const float sum = red[0] + red[1] + red[2] + red[3];
        const float sd = scores[b * NMAX + dests[b]];
        out[b] = -(sd - mx - logf(sum));
    }
}

// ---------------------------------------------------------------------------
extern "C" void kernel_launch(void* const* d_in, const int* in_sizes, int n_in,
                              void* d_out, int out_size, void* d_ws, size_t ws_size,
                              hipStream_t stream) {
    const float* nodes_hv    = (const float*)d_in[0];
    const float* class_cond  = (const float*)d_in[1];
    const float* W1          = (const float*)d_in[2];
    const float* b1          = (const float*)d_in[3];
    const float* W2          = (const float*)d_in[4];
    const float* b2          = (const float*)d_in[5];
    const float* W3          = (const float*)d_in[6];
    const float* b3          = (const float*)d_in[7];
    const int*   dirns       = (const int*)d_in[8];
    const int*   node_counts = (const int*)d_in[9];
    const int*   dests       = (const int*)d_in[10];
    float* out = (float*)d_out;

    // ws layout (16B-aligned):
    //   Wt1s: 512 KiB | Wt2s: 512 KiB | v_ws: 512 KiB | scores: 512 KiB
    ushort* Wt1s   = (ushort*)d_ws;
    ushort* Wt2s   = Wt1s + 16 * KSTR;
    float*  v_ws   = (float*)(Wt2s + 16 * KSTR);
    float*  scores = v_ws + BB * HID;

    prep_kernel<<<512, 256, 0, stream>>>(W1, W2, Wt1s, Wt2s,
                                         nodes_hv, class_cond, b1,
                                         dirns, node_counts, v_ws);
    mlp2<<<dim3(NMAX / MT, BB), 512, 0, stream>>>(
        nodes_hv, Wt1s, Wt2s, b2, W3, b3, dirns, node_counts, v_ws, scores);
    loss_kernel<<<BB, 256, 0, stream>>>(scores, dests, out);
}

// Round 6
// 286.781 us; speedup vs baseline: 6.4020x; 1.0636x over previous
//
#include <hip/hip_runtime.h>
#include <math.h>

// Problem constants
#define BB    256
#define NMAX  512
#define HH    256   // H
#define CC    64    // C
#define HID   512
#define NEGV  -1000000000.0f
#define MT    64    // d-rows per mlp block
#define NW    8     // waves per block (512 threads)
#define SA_LD 264   // A-tile leading dim: 256 + 8 pad (bf16 elems)
#define TILE  512   // ushorts per swizzled (16n x 32k) weight tile = 1KB
#define KSTR  (32 * TILE)  // ushorts per kb slab (32 n-tiles)

typedef __attribute__((ext_vector_type(8))) short short8;   // 8 bf16 = 4 VGPRs
typedef __attribute__((ext_vector_type(4))) float floatx4;  // MFMA C/D

// R10: native cast -> compiler emits v_cvt_pk_bf16_f32 pairs (RNE, identical
// numerics to the old manual round-to-nearest-even bit math, ~5x fewer VALU ops).
__device__ inline ushort f2bf(float x) {
    __bf16 b = (__bf16)x;
    return __builtin_bit_cast(ushort, b);
}

// ---------------------------------------------------------------------------
// Fused prep kernel, grid = 512 blocks x 512 threads:
//   blocks [0,128):   convert W1 k-rows [0,512) -> swizzled lane-order bf16
//                     (uses threads [0,256); rest idle — work is tiny)
//   blocks [128,256): convert W2 -> swizzled lane-order bf16
//   blocks [256,512): per-batch base vector v_b (fp32 exact).
//                     R10: 512 threads, 1 column each (was 256 thr x 2 cols)
//                     -> 2 waves/SIMD on the latency-bound GEMV.
// ---------------------------------------------------------------------------
__global__ __launch_bounds__(512) void prep_kernel(
    const float* __restrict__ W1, const float* __restrict__ W2,
    ushort* __restrict__ Wt1s, ushort* __restrict__ Wt2s,
    const float* __restrict__ nodes_hv, const float* __restrict__ class_cond,
    const float* __restrict__ b1,
    const int* __restrict__ dirns, const int* __restrict__ node_counts,
    float* __restrict__ v_ws)
{
    const int blk = blockIdx.x;
    const int t = threadIdx.x;

    __shared__ float s_conv[32][68];
    __shared__ float s_src[HH];
    __shared__ float s_cc[CC];

    if (blk < 256) {
        const float* W = (blk < 128) ? W1 : W2;
        ushort* out    = (blk < 128) ? Wt1s : Wt2s;
        const int bb  = blk & 127;
        const int kb  = bb >> 3, ntg = bb & 7;

        if (t < 256) {
            const int kl = t >> 3, nn = (t & 7) * 8;
            const float* src = W + (size_t)(kb * 32 + kl) * HID + ntg * 64 + nn;
            *(float4*)&s_conv[kl][nn]     = *(const float4*)src;
            *(float4*)&s_conv[kl][nn + 4] = *(const float4*)(src + 4);
        }
        __syncthreads();

        if (t < 256) {
            const int ntl = t >> 6, ls = t & 63;
            const int qs = ls >> 4, l15s = ls & 15;
            short8 o;
            #pragma unroll
            for (int j = 0; j < 8; ++j)
                o[j] = (short)f2bf(s_conv[qs * 8 + j][ntl * 16 + l15s]);
            const int nt = ntg * 4 + ntl;
            *(short8*)(out + ((size_t)(kb * 32 + nt)) * TILE + ls * 8) = o;
        }
    } else {
        const int b = blk - 256;
        const int nc   = node_counts[b];
        const int dirn = dirns[b];
        const int src_idx = nc - 1;

        if (t < HH) s_src[t] = nodes_hv[((size_t)b * NMAX + src_idx) * HH + t];
        else if (t < HH + CC) s_cc[t - HH] = class_cond[b * CC + (t - HH)];
        __syncthreads();

        const int srcoff = (dirn == 1) ? HH : 0;

        const int j = t;              // one HID column per thread
        float acc0 = b1[j];

        #pragma unroll 8
        for (int r = 0; r < HH; ++r)
            acc0 += s_src[r] * W1[(size_t)(srcoff + r) * HID + j];
        #pragma unroll 8
        for (int c = 0; c < CC; ++c)
            acc0 += s_cc[c] * W1[(size_t)(2 * HH + c) * HID + j];

        v_ws[b * HID + j] = acc0;
    }
}

// ---------------------------------------------------------------------------
// Kernel 2: MFMA MLP, M=64, 512 threads (8 waves). grid = (NMAX/MT, B).
// Verified structure (full h1 in 64 KB LDS union, 2 blocks/CU) + R9 depth-1
// register double-buffer of weight tiles + R10: cvt_pk conversions and T5
// setprio around each K-step's MFMA cluster (2 phase-offset blocks/CU ->
// independent-block regime where setprio pays, cf. m191 vs m190).
// Register budget note: acc(64 AGPR) + working(64 VGPR) = 128 = (512,4) cap.
// Do NOT add live state across the layer loops (R8 post-mortem: reg cap
// below need -> total spill, 12x slower).
// ---------------------------------------------------------------------------
__global__ __launch_bounds__(512, 4) void mlp2(
    const float* __restrict__ nodes_hv,
    const ushort* __restrict__ Wt1s, const ushort* __restrict__ Wt2s,
    const float* __restrict__ b2, const float* __restrict__ W3,
    const float* __restrict__ b3,
    const int* __restrict__ dirns, const int* __restrict__ node_counts,
    const float* __restrict__ v_ws, float* __restrict__ scores)
{
    const int b  = blockIdx.y;
    const int d0 = blockIdx.x * MT;
    const int t  = threadIdx.x;
    const int lane = t & 63, wv = t >> 6;     // wv in [0,8)
    const int l15 = lane & 15, q = lane >> 4;

    __shared__ ushort s_u[32768];   // 64 KB union

    const int nc = node_counts[b];

    // Block-uniform early exit: whole tile masked off
    if (d0 >= nc - 1) {
        if (t < MT) scores[b * NMAX + d0 + t] = NEGV;
        return;
    }

    // dirn==1: cand occupies x[0:256) -> W1 k-rows [0:256) -> kb0=0; else kb0=8
    const int kb0 = (dirns[b] == 1) ? 0 : 8;

    // ---- stage cand tile (MT x 256 fp32 -> bf16 LDS, leading dim SA_LD) ----
    {
        const float4* src4 = (const float4*)nodes_hv + ((size_t)b * NMAX + d0) * (HH / 4);
        #pragma unroll
        for (int i = 0; i < (MT * HH / 4) / 512; ++i) {   // 8 iters
            int idx = t + i * 512;
            int row = idx >> 6, c4 = idx & 63;
            float4 v = src4[idx];
            ushort4 p;
            p.x = f2bf(v.x); p.y = f2bf(v.y); p.z = f2bf(v.z); p.w = f2bf(v.w);
            *(ushort4*)&s_u[row * SA_LD + c4 * 4] = p;
        }
    }
    __syncthreads();

    floatx4 acc[4][4];
    #pragma unroll
    for (int mb = 0; mb < 4; ++mb)
        #pragma unroll
        for (int tn = 0; tn < 4; ++tn)
            acc[mb][tn] = (floatx4){0.f, 0.f, 0.f, 0.f};

    // ---- layer 1: K = 256 (8 K-steps of 32), depth-1 weight prefetch ----
    {
        const ushort* wb1 = Wt1s + ((size_t)kb0 * 32 + wv * 4) * TILE + lane * 8;
        short8 bcur[4], bnxt[4];
        #pragma unroll
        for (int tn = 0; tn < 4; ++tn)
            bcur[tn] = *(const short8*)(wb1 + tn * TILE);
        #pragma unroll
        for (int ks = 0; ks < 8; ++ks) {
            if (ks < 7) {
                const ushort* wp = wb1 + (size_t)(ks + 1) * KSTR;
                #pragma unroll
                for (int tn = 0; tn < 4; ++tn)
                    bnxt[tn] = *(const short8*)(wp + tn * TILE);
            }
            __builtin_amdgcn_s_setprio(1);
            #pragma unroll
            for (int mb = 0; mb < 4; ++mb) {
                const short8 a = *(const short8*)&s_u[(mb * 16 + l15) * SA_LD + ks * 32 + q * 8];
                #pragma unroll
                for (int tn = 0; tn < 4; ++tn)
                    acc[mb][tn] = __builtin_amdgcn_mfma_f32_16x16x32_bf16(a, bcur[tn], acc[mb][tn], 0, 0, 0);
            }
            __builtin_amdgcn_s_setprio(0);
            #pragma unroll
            for (int tn = 0; tn < 4; ++tn)
                bcur[tn] = bnxt[tn];
        }
    }
    __syncthreads();   // all waves done reading cand tile before h1 overwrites union

    const int n0 = wv * 64;

    // ---- epilogue 1: h1 = relu(acc + v_b) -> fragment-tiled LDS ----
    // n = n0 + tn*16 + l15 -> ks_w = wv*2 + (tn>>1); qr = ((tn&1)<<1)+(l15>>3); j_w = l15&7
    {
        const int j_w = l15 & 7;
        #pragma unroll
        for (int tn = 0; tn < 4; ++tn) {
            const int n = n0 + tn * 16 + l15;
            const float v = v_ws[b * HID + n];
            const int ks_w = wv * 2 + (tn >> 1);
            const int qr   = ((tn & 1) << 1) + (l15 >> 3);
            #pragma unroll
            for (int mb = 0; mb < 4; ++mb) {
                #pragma unroll
                for (int r = 0; r < 4; ++r) {
                    float h = acc[mb][tn][r] + v;          // C/D: row=q*4+r, col=l15
                    h = h > 0.f ? h : 0.f;
                    s_u[((mb * 16 + ks_w) * 64 + qr * 16 + q * 4 + r) * 8 + j_w] = f2bf(h);
                }
            }
        }
    }
    __syncthreads();

    // ---- layer 2: K = 512 (16 K-steps), depth-1 weight prefetch ----
    #pragma unroll
    for (int mb = 0; mb < 4; ++mb)
        #pragma unroll
        for (int tn = 0; tn < 4; ++tn)
            acc[mb][tn] = (floatx4){0.f, 0.f, 0.f, 0.f};
    {
        const ushort* wb2 = Wt2s + ((size_t)wv * 4) * TILE + lane * 8;
        short8 bcur[4], bnxt[4];
        #pragma unroll
        for (int tn = 0; tn < 4; ++tn)
            bcur[tn] = *(const short8*)(wb2 + tn * TILE);
        #pragma unroll
        for (int ks = 0; ks < 16; ++ks) {
            if (ks < 15) {
                const ushort* wp = wb2 + (size_t)(ks + 1) * KSTR;
                #pragma unroll
                for (int tn = 0; tn < 4; ++tn)
                    bnxt[tn] = *(const short8*)(wp + tn * TILE);
            }
            __builtin_amdgcn_s_setprio(1);
            #pragma unroll
            for (int mb = 0; mb < 4; ++mb) {
                const short8 a = *(const short8*)&s_u[((mb * 16 + ks) * 64 + lane) * 8];
                #pragma unroll
                for (int tn = 0; tn < 4; ++tn)
                    acc[mb][tn] = __builtin_amdgcn_mfma_f32_16x16x32_bf16(a, bcur[tn], acc[mb][tn], 0, 0, 0);
            }
            __builtin_amdgcn_s_setprio(0);
            #pragma unroll
            for (int tn = 0; tn < 4; ++tn)
                bcur[tn] = bnxt[tn];
        }
    }

    // ---- epilogue 2: p = relu(acc + b2) . W3, reduce over n ----
    float p[4][4] = {{0,0,0,0},{0,0,0,0},{0,0,0,0},{0,0,0,0}};
    #pragma unroll
    for (int tn = 0; tn < 4; ++tn) {
        const int n  = n0 + tn * 16 + l15;
        const float bb = b2[n];
        const float w3 = W3[n];
        #pragma unroll
        for (int mb = 0; mb < 4; ++mb)
            #pragma unroll
            for (int r = 0; r < 4; ++r) {
                float h = acc[mb][tn][r] + bb;
                h = h > 0.f ? h : 0.f;
                p[mb][r] += h * w3;
            }
    }
    __syncthreads();   // h1 region dead; safe to reuse union for s_red
    float* s_red = (float*)s_u;   // [8 waves][MT]
    #pragma unroll
    for (int mb = 0; mb < 4; ++mb)
        #pragma unroll
        for (int r = 0; r < 4; ++r) {
            float v = p[mb][r];
            v += __shfl_xor(v, 1, 64);
            v += __shfl_xor(v, 2, 64);
            v += __shfl_xor(v, 4, 64);
            v += __shfl_xor(v, 8, 64);
            if (l15 == 0) s_red[wv * MT + mb * 16 + q * 4 + r] = v;
        }
    __syncthreads();
    if (t < MT) {
        float s = b3[0];
        #pragma unroll
        for (int w = 0; w < NW; ++w) s += s_red[w * MT + t];
        const int d = d0 + t;
        scores[b * NMAX + d] = (d < nc - 1) ? s : NEGV;
    }
}

// ---------------------------------------------------------------------------
// Kernel 3: per-batch masked log-softmax NLL. grid = B, block = 256.
// ---------------------------------------------------------------------------
__global__ __launch_bounds__(256) void loss_kernel(
    const float* __restrict__ scores, const int* __restrict__ dests,
    float* __restrict__ out)
{
    const int b = blockIdx.x;
    const int t = threadIdx.x;
    __shared__ float red[4];

    const float s0 = scores[b * NMAX + t];
    const float s1 = scores[b * NMAX + t + 256];

    const int lane = t & 63, wv = t >> 6;

    float mx = fmaxf(s0, s1);
    #pragma unroll
    for (int off = 32; off > 0; off >>= 1) mx = fmaxf(mx, __shfl_down(mx, off, 64));
    if (lane == 0) red[wv] = mx;
    __syncthreads();
    mx = fmaxf(fmaxf(red[0], red[1]), fmaxf(red[2], red[3]));
    __syncthreads();

    float e = __expf(s0 - mx) + __expf(s1 - mx);
    #pragma unroll
    for (int off = 32; off > 0; off >>= 1) e += __shfl_down(e, off, 64);
    if (lane == 0) red[wv] = e;
    __syncthreads();

    if (t == 0) {
        const float sum = red[0] + red[1] + red[2] + red[3];
        const float sd = scores[b * NMAX + dests[b]];
        out[b] = -(sd - mx - logf(sum));
    }
}

// ---------------------------------------------------------------------------
extern "C" void kernel_launch(void* const* d_in, const int* in_sizes, int n_in,
                              void* d_out, int out_size, void* d_ws, size_t ws_size,
                              hipStream_t stream) {
    const float* nodes_hv    = (const float*)d_in[0];
    const float* class_cond  = (const float*)d_in[1];
    const float* W1          = (const float*)d_in[2];
    const float* b1          = (const float*)d_in[3];
    const float* W2          = (const float*)d_in[4];
    const float* b2          = (const float*)d_in[5];
    const float* W3          = (const float*)d_in[6];
    const float* b3          = (const float*)d_in[7];
    const int*   dirns       = (const int*)d_in[8];
    const int*   node_counts = (const int*)d_in[9];
    const int*   dests       = (const int*)d_in[10];
    float* out = (float*)d_out;

    // ws layout (16B-aligned):
    //   Wt1s: 512 KiB | Wt2s: 512 KiB | v_ws: 512 KiB | scores: 512 KiB
    ushort* Wt1s   = (ushort*)d_ws;
    ushort* Wt2s   = Wt1s + 16 * KSTR;
    float*  v_ws   = (float*)(Wt2s + 16 * KSTR);
    float*  scores = v_ws + BB * HID;

    prep_kernel<<<512, 512, 0, stream>>>(W1, W2, Wt1s, Wt2s,
                                         nodes_hv, class_cond, b1,
                                         dirns, node_counts, v_ws);
    mlp2<<<dim3(NMAX / MT, BB), 512, 0, stream>>>(
        nodes_hv, Wt1s, Wt2s, b2, W3, b3, dirns, node_counts, v_ws, scores);
    loss_kernel<<<BB, 256, 0, stream>>>(scores, dests, out);
}